// Round 3
// baseline (47.837 us; speedup 1.0000x reference)
//
#include <hip/hip_runtime.h>
#include <hip/hip_bf16.h>

namespace {

struct c32 { float x, y; };

__device__ __forceinline__ c32 cmul(c32 a, c32 b) {
    return { a.x*b.x - a.y*b.y, a.x*b.y + a.y*b.x };
}
__device__ __forceinline__ c32 cadd(c32 a, c32 b) { return { a.x+b.x, a.y+b.y }; }

// PennyLane Rot(phi,theta,omega) = RZ(omega) RY(theta) RZ(phi): [[a,b],[c,d]]
__device__ __forceinline__ void rot_mat(float ph, float th, float om, c32 m[4]) {
    float sth, cth; sincosf(0.5f*th, &sth, &cth);
    float sa, ca;  sincosf(-0.5f*(ph+om), &sa, &ca);   // e^{-i(phi+omega)/2}
    float sb, cb;  sincosf(0.5f*(ph-om), &sb, &cb);    // e^{+i(phi-omega)/2}
    m[0] = {  ca*cth,  sa*cth };
    m[1] = { -cb*sth, -sb*sth };
    m[2] = {  cb*sth, -sb*sth };
    m[3] = {  ca*cth, -sa*cth };
}

#define INV_SQRT2F 0.70710678118654752440f

// static scratch: no dependence on ws_size. Fully rewritten before each read.
__device__ float2 g_state[32 * 65536];   // 16 MiB
__device__ float  g_part[32 * 8 * 16];

// K1: block = (batch b, slice t2 = wires 13..15). Local wires 0..12 (bit w = wire w).
// State after FULL ring1 computed analytically from the product state:
//   psi[y] = prod_w v_w[x_w],  x = y ^ ((y<<1)&0xFFFE) ^ 3*y15
// Then Rot1 on wires 0..12 (program order; all local). Linear write of slice.
__global__ __launch_bounds__(512)
void qphase1(const float* __restrict__ xin, const float* __restrict__ wts) {
    __shared__ c32 S[8192];
    __shared__ c32 V[16][2];   // v_w = Rot0 * H * RY(x_w) |0>
    __shared__ c32 M[16][4];   // Rot1 matrices
    const int tid = threadIdx.x;
    const int b  = blockIdx.x >> 3;
    const int t2 = blockIdx.x & 7;

    if (tid < 16) {
        const int w = tid;
        float s, c; sincosf(0.5f * xin[b*16 + w], &s, &c);
        const float h0 = (c + s) * INV_SQRT2F;   // H * RY|0>
        const float h1 = (c - s) * INV_SQRT2F;
        c32 m[4]; rot_mat(wts[w*3+0], wts[w*3+1], wts[w*3+2], m);
        V[w][0] = { m[0].x*h0 + m[1].x*h1, m[0].y*h0 + m[1].y*h1 };
        V[w][1] = { m[2].x*h0 + m[3].x*h1, m[2].y*h0 + m[3].y*h1 };
    } else if (tid < 32) {
        const int w = tid - 16;
        c32 m[4]; rot_mat(wts[48 + w*3+0], wts[48 + w*3+1], wts[48 + w*3+2], m);
        M[w][0]=m[0]; M[w][1]=m[1]; M[w][2]=m[2]; M[w][3]=m[3];
    }
    __syncthreads();

    c32 rv0[13], rv1[13];
    #pragma unroll
    for (int w=0; w<13; ++w) { rv0[w]=V[w][0]; rv1[w]=V[w][1]; }

    const int t20 = t2 & 1, t21 = (t2 >> 1) & 1, t22 = (t2 >> 2) & 1;
    // x14 = y14^y13, x15 = y15^y14; x13 = y13^y12 handled via q3 below
    const c32 hi3 = cmul(V[14][t21 ^ t20], V[15][t22 ^ t21]);
    const c32 hiA = cmul(hi3, V[13][t20]);       // q3 = 0
    const c32 hiB = cmul(hi3, V[13][t20 ^ 1]);   // q3 = 1

    // x bits 0..8: x0 = y0^y15, x1 = y1^y0^y15, xw = yw^y(w-1)
    const unsigned xlo = (unsigned)tid ^ (((unsigned)tid << 1) & 0x1FEu) ^ (t22 ? 3u : 0u);
    c32 plo = { 1.f, 0.f };
    #pragma unroll
    for (int w=0; w<9; ++w) {
        const c32 vv = ((xlo >> w) & 1u) ? rv1[w] : rv0[w];
        plo = cmul(plo, vv);
    }
    // x9 = q0 ^ j8
    const int j8 = (tid >> 8) & 1;
    const c32 p9a = cmul(plo, j8 ? rv1[9] : rv0[9]);   // q0 = 0
    const c32 p9b = cmul(plo, j8 ? rv0[9] : rv1[9]);   // q0 = 1
    #pragma unroll
    for (int q=0; q<16; ++q) {
        const int c10 = (q ^ (q>>1)) & 1;          // x10 = q1^q0
        const int c11 = ((q>>1) ^ (q>>2)) & 1;     // x11 = q2^q1
        const int c12 = ((q>>2) ^ (q>>3)) & 1;     // x12 = q3^q2
        c32 hi = cmul(cmul(c10 ? rv1[10] : rv0[10], c11 ? rv1[11] : rv0[11]),
                      c12 ? rv1[12] : rv0[12]);
        hi = cmul(hi, (q >= 8) ? hiB : hiA);
        S[tid + (q<<9)] = cmul((q & 1) ? p9b : p9a, hi);
    }

    // Rot1 on wires 0..12 (program order)
    for (int w=0; w<=12; ++w) {
        __syncthreads();
        const c32 a = M[w][0], bb = M[w][1], c = M[w][2], d = M[w][3];
        const int mlo = (1<<w) - 1;
        #pragma unroll
        for (int q=0; q<8; ++q) {
            const int p = tid + (q<<9);
            const int j0 = ((p & ~mlo) << 1) | (p & mlo);
            const int j1 = j0 | (1<<w);
            const c32 s0 = S[j0], s1 = S[j1];
            S[j0] = cadd(cmul(a, s0), cmul(bb, s1));
            S[j1] = cadd(cmul(c, s0), cmul(d, s1));
        }
    }
    __syncthreads();

    float2* g = g_state + ((size_t)b << 16) + (t2 << 13);
    #pragma unroll
    for (int q=0; q<16; ++q) {
        const int j = tid + (q<<9);
        g[j] = make_float2(S[j].x, S[j].y);
    }
}

// K2: block = (b, t = wires {3,5,7}). Local wires {0,1,2,4,6,8..15}; pure
// bit-relabel gather. Rot1 on wires 13,14,15 (local bits 10,11,12). Ring2
// folded into the measurement sign index by forward-applying all 16 CNOTs
// C(w,(w+2)%16) sequentially in program order (computes F^{-1}(i)).
__global__ __launch_bounds__(512)
void qphase2(const float* __restrict__ wts) {
    __shared__ c32 S[8192];
    __shared__ c32 M3[3][4];
    __shared__ float R[8][16];
    const int tid = threadIdx.x;
    const int b = blockIdx.x >> 3;
    const int t = blockIdx.x & 7;

    if (tid < 3) {
        const int w = 13 + tid;
        c32 m[4]; rot_mat(wts[48 + w*3+0], wts[48 + w*3+1], wts[48 + w*3+2], m);
        M3[tid][0]=m[0]; M3[tid][1]=m[1]; M3[tid][2]=m[2]; M3[tid][3]=m[3];
    }
    __syncthreads();

    const unsigned base = ((unsigned)(t&1) << 3) | ((unsigned)((t>>1)&1) << 5)
                        | ((unsigned)((t>>2)&1) << 7);
    const float2* g = g_state + ((size_t)b << 16);
    #pragma unroll
    for (int q=0; q<16; ++q) {
        const int j = tid + (q<<9);
        const unsigned i = (unsigned)(j & 7) | ((unsigned)(j & 8) << 1)
                         | ((unsigned)(j & 16) << 2) | ((unsigned)(j & 0x1FE0) << 3) | base;
        const float2 v = g[i];
        S[j] = { v.x, v.y };
    }

    #pragma unroll
    for (int gi=0; gi<3; ++gi) {
        __syncthreads();
        const int lb = 10 + gi;                 // wires 13,14,15
        const c32 a = M3[gi][0], bb = M3[gi][1];
        const c32 c = M3[gi][2], d  = M3[gi][3];
        const int mlo = (1<<lb) - 1;
        #pragma unroll
        for (int q=0; q<8; ++q) {
            const int p = tid + (q<<9);
            const int j0 = ((p & ~mlo) << 1) | (p & mlo);
            const int j1 = j0 | (1<<lb);
            const c32 s0 = S[j0], s1 = S[j1];
            S[j0] = cadd(cmul(a, s0), cmul(bb, s1));
            S[j1] = cadd(cmul(c, s0), cmul(d, s1));
        }
    }
    __syncthreads();

    float acc[16];
    #pragma unroll
    for (int w=0; w<16; ++w) acc[w] = 0.f;

    for (int q=0; q<16; ++q) {
        const int j = tid + (q<<9);
        const unsigned i = (unsigned)(j & 7) | ((unsigned)(j & 8) << 1)
                         | ((unsigned)(j & 16) << 2) | ((unsigned)(j & 0x1FE0) << 3) | base;
        unsigned f = i;
        // ring2 C(w,(w+2)%16), w = 0..15, exact program order
        f ^= ((f >> 0) & 1u) << 2;   f ^= ((f >> 1) & 1u) << 3;
        f ^= ((f >> 2) & 1u) << 4;   f ^= ((f >> 3) & 1u) << 5;
        f ^= ((f >> 4) & 1u) << 6;   f ^= ((f >> 5) & 1u) << 7;
        f ^= ((f >> 6) & 1u) << 8;   f ^= ((f >> 7) & 1u) << 9;
        f ^= ((f >> 8) & 1u) << 10;  f ^= ((f >> 9) & 1u) << 11;
        f ^= ((f >> 10) & 1u) << 12; f ^= ((f >> 11) & 1u) << 13;
        f ^= ((f >> 12) & 1u) << 14; f ^= ((f >> 13) & 1u) << 15;
        f ^= ((f >> 14) & 1u) << 0;  f ^= ((f >> 15) & 1u) << 1;
        const c32 s = S[j];
        const float p2 = s.x*s.x + s.y*s.y;
        #pragma unroll
        for (int w=0; w<16; ++w) {
            const unsigned sgn = ((f >> w) & 1u) << 31;
            acc[w] += __uint_as_float(__float_as_uint(p2) ^ sgn);
        }
    }

    #pragma unroll
    for (int w=0; w<16; ++w)
        for (int o=32; o>0; o>>=1) acc[w] += __shfl_down(acc[w], o);

    const int lane = tid & 63, wv = tid >> 6;
    if (lane == 0) {
        #pragma unroll
        for (int w=0; w<16; ++w) R[wv][w] = acc[w];
    }
    __syncthreads();
    if (tid < 16) {
        float ssum = 0.f;
        #pragma unroll
        for (int k=0; k<8; ++k) ssum += R[k][tid];
        g_part[((b*8 + t) << 4) + tid] = ssum;
    }
}

// Output is FLOAT32 (the reference returns float32; d_out follows the
// reference's output dtype).
__global__ void qreduce(float* __restrict__ out) {
    const int idx = threadIdx.x;           // 512 = 32 batch x 16 wires
    const int b = idx >> 4, w = idx & 15;
    float s = 0.f;
    #pragma unroll
    for (int t=0; t<8; ++t) s += g_part[((b*8 + t) << 4) + w];
    out[idx] = s;
}

} // namespace

extern "C" void kernel_launch(void* const* d_in, const int* in_sizes, int n_in,
                              void* d_out, int out_size, void* d_ws, size_t ws_size,
                              hipStream_t stream) {
    (void)in_sizes; (void)n_in; (void)out_size; (void)d_ws; (void)ws_size;
    const float* xin = (const float*)d_in[0];   // (32,16) float32
    const float* wts = (const float*)d_in[1];   // (2,16,3) float32
    float* out = (float*)d_out;

    qphase1<<<dim3(256), dim3(512), 0, stream>>>(xin, wts);
    qphase2<<<dim3(256), dim3(512), 0, stream>>>(wts);
    qreduce<<<dim3(1),   dim3(512), 0, stream>>>(out);
}

// Round 4
// 12.008 us; speedup vs baseline: 3.9838x; 3.9838x over previous
//
#include <hip/hip_runtime.h>

namespace {

struct c32 { float x, y; };

__device__ __forceinline__ c32 cmul(c32 a, c32 b) {
    return { a.x*b.x - a.y*b.y, a.x*b.y + a.y*b.x };
}
__device__ __forceinline__ c32 cmulc(c32 a, c32 b) {   // a * conj(b)
    return { a.x*b.x + a.y*b.y, a.y*b.x - a.x*b.y };
}

// PennyLane Rot(phi,theta,omega) = RZ(omega) RY(theta) RZ(phi): [[m0,m1],[m2,m3]]
__device__ __forceinline__ void rot_mat(float ph, float th, float om, c32 m[4]) {
    float sth, cth; sincosf(0.5f*th, &sth, &cth);
    float sa, ca;  sincosf(-0.5f*(ph+om), &sa, &ca);
    float sb, cb;  sincosf(0.5f*(ph-om), &sb, &cb);
    m[0] = {  ca*cth,  sa*cth };
    m[1] = { -cb*sth, -sb*sth };
    m[2] = {  cb*sth, -sb*sth };
    m[3] = {  ca*cth, -sa*cth };
}

#define INV_SQRT2F 0.70710678118654752440f

// E_w(b) via exact transfer-matrix contraction.
//   v_k = Rot0_k H RY(x_k) |0>            (product state before ring1)
//   O_k = Rot1_k^dag Z Rot1_k  if k in S_w else I   (ring2 folded: S_w = row w of M2)
//   E_w = sum_{z,z'} prod_k v_k[u_k] conj(v_k[u'_k]) O_k[z'_k, z_k]
//   with u_k = z_k ^ z_{k-1} (k>=2), u_0 = z_0 ^ z_15, u_1 = z_1 ^ z_0 ^ z_15
// Chain over k with 4-state bond s=(z_k, z'_k); the z_15 wraparound is handled
// by the 4 boundary values beta=(bz,bzp), one per lane in each 4-lane group.
__global__ __launch_bounds__(64)
void qtn(const float* __restrict__ xin, const float* __restrict__ wts,
         float* __restrict__ out) {
    __shared__ c32 V[16][2];
    __shared__ c32 OZ[16][2][2];
    __shared__ unsigned SC[16];   // SC[k] = M2 * e_k ; bit w = [k in S_w]
    const int tid = threadIdx.x;
    const int b = blockIdx.x;

    if (tid < 16) {
        const int k = tid;
        float s, c; sincosf(0.5f * xin[b*16 + k], &s, &c);
        const float h0 = (c + s) * INV_SQRT2F;   // H * RY(x)|0>
        const float h1 = (c - s) * INV_SQRT2F;
        c32 m0[4]; rot_mat(wts[k*3+0], wts[k*3+1], wts[k*3+2], m0);
        V[k][0] = { m0[0].x*h0 + m0[1].x*h1, m0[0].y*h0 + m0[1].y*h1 };
        V[k][1] = { m0[2].x*h0 + m0[3].x*h1, m0[2].y*h0 + m0[3].y*h1 };

        c32 r[4]; rot_mat(wts[48 + k*3+0], wts[48 + k*3+1], wts[48 + k*3+2], r);
        // O = R^dag Z R, R = [[r0,r1],[r2,r3]]:
        // O[i][j] = conj(R[0][i])R[0][j] - conj(R[1][i])R[1][j]
        OZ[k][0][0] = { (r[0].x*r[0].x + r[0].y*r[0].y) - (r[2].x*r[2].x + r[2].y*r[2].y), 0.f };
        OZ[k][1][1] = { (r[1].x*r[1].x + r[1].y*r[1].y) - (r[3].x*r[3].x + r[3].y*r[3].y), 0.f };
        const c32 t1 = cmulc(r[1], r[0]);   // conj(r0)*r1
        const c32 t2 = cmulc(r[3], r[2]);   // conj(r2)*r3
        const c32 o01 = { t1.x - t2.x, t1.y - t2.y };
        OZ[k][0][1] = o01;
        OZ[k][1][0] = { o01.x, -o01.y };

        // ring2 CNOT(w,(w+2)%16), w=0..15 program order, applied to e_k
        unsigned f = 1u << k;
        f ^= ((f >> 0) & 1u) << 2;   f ^= ((f >> 1) & 1u) << 3;
        f ^= ((f >> 2) & 1u) << 4;   f ^= ((f >> 3) & 1u) << 5;
        f ^= ((f >> 4) & 1u) << 6;   f ^= ((f >> 5) & 1u) << 7;
        f ^= ((f >> 6) & 1u) << 8;   f ^= ((f >> 7) & 1u) << 9;
        f ^= ((f >> 8) & 1u) << 10;  f ^= ((f >> 9) & 1u) << 11;
        f ^= ((f >> 10) & 1u) << 12; f ^= ((f >> 11) & 1u) << 13;
        f ^= ((f >> 12) & 1u) << 14; f ^= ((f >> 13) & 1u) << 15;
        f ^= ((f >> 14) & 1u) << 0;  f ^= ((f >> 15) & 1u) << 1;
        SC[k] = f;
    }
    __syncthreads();

    const int w   = tid >> 2;         // wire being measured
    const int bz  = tid & 1;          // beta: z_15
    const int bzp = (tid >> 1) & 1;   // beta: z'_15

    c32 m[4];
    // site 0: u0 = z0 ^ bz, u'0 = z'0 ^ bzp
    {
        const bool mem = (SC[0] >> w) & 1u;
        #pragma unroll
        for (int s=0; s<4; ++s) {
            const int z0 = s & 1, z0p = (s >> 1) & 1;
            const c32 t = cmulc(V[0][z0 ^ bz], V[0][z0p ^ bzp]);
            const c32 o = mem ? OZ[0][z0p][z0] : c32{ (z0p==z0) ? 1.f : 0.f, 0.f };
            m[s] = cmul(t, o);
        }
    }
    // sites 1..14 (site 1 additionally XORs beta into the v index)
    #pragma unroll 1
    for (int k=1; k<=14; ++k) {
        const int xk = (k==1) ? bz  : 0;
        const int xb = (k==1) ? bzp : 0;
        const bool mem = (SC[k] >> w) & 1u;
        c32 g[2][2], h[2][2], nm[4];
        #pragma unroll
        for (int z0=0; z0<2; ++z0)
        #pragma unroll
        for (int z1p=0; z1p<2; ++z1p) {
            c32 acc = {0.f, 0.f};
            #pragma unroll
            for (int z0p=0; z0p<2; ++z0p) {
                const c32 vv = V[k][(z1p ^ z0p ^ xb) & 1];
                const c32 mm = m[z0 | (z0p<<1)];
                acc.x += vv.x*mm.x + vv.y*mm.y;    // conj(vv)*mm
                acc.y += vv.x*mm.y - vv.y*mm.x;
            }
            g[z0][z1p] = acc;
        }
        #pragma unroll
        for (int z1=0; z1<2; ++z1)
        #pragma unroll
        for (int z1p=0; z1p<2; ++z1p) {
            c32 acc = {0.f, 0.f};
            #pragma unroll
            for (int z0=0; z0<2; ++z0) {
                const c32 vv = V[k][(z1 ^ z0 ^ xk) & 1];
                const c32 gg = g[z0][z1p];
                acc.x += vv.x*gg.x - vv.y*gg.y;    // vv*gg
                acc.y += vv.x*gg.y + vv.y*gg.x;
            }
            h[z1][z1p] = acc;
        }
        #pragma unroll
        for (int z1=0; z1<2; ++z1)
        #pragma unroll
        for (int z1p=0; z1p<2; ++z1p) {
            const c32 o = mem ? OZ[k][z1p][z1] : c32{ (z1p==z1) ? 1.f : 0.f, 0.f };
            nm[z1 | (z1p<<1)] = cmul(o, h[z1][z1p]);
        }
        m[0]=nm[0]; m[1]=nm[1]; m[2]=nm[2]; m[3]=nm[3];
    }
    // site 15: u15 = bz ^ z14, u'15 = bzp ^ z'14, O15[bzp][bz] fixed by beta
    float r;
    {
        const bool mem = (SC[15] >> w) & 1u;
        c32 gg[2];
        #pragma unroll
        for (int z14=0; z14<2; ++z14) {
            c32 acc = {0.f, 0.f};
            #pragma unroll
            for (int z14p=0; z14p<2; ++z14p) {
                const c32 vv = V[15][(bzp ^ z14p) & 1];
                const c32 mm = m[z14 | (z14p<<1)];
                acc.x += vv.x*mm.x + vv.y*mm.y;    // conj(vv)*mm
                acc.y += vv.x*mm.y - vv.y*mm.x;
            }
            gg[z14] = acc;
        }
        c32 ee = {0.f, 0.f};
        #pragma unroll
        for (int z14=0; z14<2; ++z14) {
            const c32 vv = V[15][(bz ^ z14) & 1];
            ee.x += vv.x*gg[z14].x - vv.y*gg[z14].y;
            ee.y += vv.x*gg[z14].y + vv.y*gg[z14].x;
        }
        const c32 o = mem ? OZ[15][bzp][bz] : c32{ (bzp==bz) ? 1.f : 0.f, 0.f };
        r = o.x*ee.x - o.y*ee.y;   // real part of o*ee
    }

    // sum the 4 beta lanes of each wire group
    r += __shfl_xor(r, 1);
    r += __shfl_xor(r, 2);
    if ((tid & 3) == 0) out[b*16 + w] = r;
}

} // namespace

extern "C" void kernel_launch(void* const* d_in, const int* in_sizes, int n_in,
                              void* d_out, int out_size, void* d_ws, size_t ws_size,
                              hipStream_t stream) {
    (void)in_sizes; (void)n_in; (void)out_size; (void)d_ws; (void)ws_size;
    const float* xin = (const float*)d_in[0];   // (32,16) float32
    const float* wts = (const float*)d_in[1];   // (2,16,3) float32
    float* out = (float*)d_out;

    qtn<<<dim3(32), dim3(64), 0, stream>>>(xin, wts, out);
}